// Round 1
// baseline (1032.486 us; speedup 1.0000x reference)
//
#include <hip/hip_runtime.h>
#include <math.h>

#define B_  8
#define C_  384
#define H_  32
#define W_  32
#define NS_ 1024
#define HEADS_ 12
#define HD_ 32
#define GROUPS_ 3
#define CG_ 128
#define EPS_ 1e-5f

// ---------------------------------------------------------------------------
// GEMM: Y[b,m,n] = sum_k Wm[m,k] * X[b,k,n] + bias[m] (+ res[b,m,n] optional)
// X: (B, K, NS_), Wm: (M, K) row-major, Y: (B, M, NS_)
// tile 64(M) x 128(N), K-chunk 16, 128 threads, 8x8 micro-tile
// ---------------------------------------------------------------------------
#define TM 64
#define TN 128
#define TKK 16
// pad 4 floats per 32 so the 16 strided 32B read-chunks map to distinct bank quads (2-way max)
#define XP(n) ((n) + (((n) >> 5) << 2))

__global__ __launch_bounds__(128) void gemm_bcn(
    const float* __restrict__ X, const float* __restrict__ Wm,
    const float* __restrict__ bias, const float* __restrict__ res,
    float* __restrict__ Y, int K, int M)
{
  __shared__ float Ws[TKK][TM];                 // [k][m]
  __shared__ float Xs[TKK][TN + (TN >> 3)];     // [k][n-padded], 144

  int b  = blockIdx.z;
  int m0 = blockIdx.y * TM;
  int n0 = blockIdx.x * TN;
  int tid = threadIdx.x;
  int ty = tid >> 4;        // 0..7
  int tx = tid & 15;        // 0..15

  float acc[8][8];
#pragma unroll
  for (int i = 0; i < 8; ++i)
#pragma unroll
    for (int j = 0; j < 8; ++j) acc[i][j] = 0.f;

  const float* Xb = X + (size_t)b * K * NS_;
  int wi = tid >> 2;            // 0..31
  int wj = (tid & 3) << 2;      // 0,4,8,12
  int xk = tid >> 3;            // 0..15
  int xs = (tid & 7) << 2;      // 0..28

  for (int kc = 0; kc < K; kc += TKK) {
    // prefetch to regs
    float4 w0 = *(const float4*)(Wm + (size_t)(m0 + wi) * K + kc + wj);
    float4 w1 = *(const float4*)(Wm + (size_t)(m0 + wi + 32) * K + kc + wj);
    const float* xsrc = Xb + (size_t)(kc + xk) * NS_ + n0 + xs;
    float4 xv0 = *(const float4*)(xsrc);
    float4 xv1 = *(const float4*)(xsrc + 32);
    float4 xv2 = *(const float4*)(xsrc + 64);
    float4 xv3 = *(const float4*)(xsrc + 96);

    __syncthreads();   // previous iteration consumers done
    Ws[wj+0][wi] = w0.x; Ws[wj+1][wi] = w0.y; Ws[wj+2][wi] = w0.z; Ws[wj+3][wi] = w0.w;
    Ws[wj+0][wi+32] = w1.x; Ws[wj+1][wi+32] = w1.y; Ws[wj+2][wi+32] = w1.z; Ws[wj+3][wi+32] = w1.w;
    *(float4*)&Xs[xk][XP(xs)]      = xv0;
    *(float4*)&Xs[xk][XP(xs+32)]   = xv1;
    *(float4*)&Xs[xk][XP(xs+64)]   = xv2;
    *(float4*)&Xs[xk][XP(xs+96)]   = xv3;
    __syncthreads();

#pragma unroll
    for (int kk = 0; kk < TKK; ++kk) {
      float a[8], bb[8];
      *(float4*)&a[0]  = *(const float4*)&Ws[kk][ty*8];
      *(float4*)&a[4]  = *(const float4*)&Ws[kk][ty*8+4];
      *(float4*)&bb[0] = *(const float4*)&Xs[kk][XP(tx*8)];
      *(float4*)&bb[4] = *(const float4*)&Xs[kk][XP(tx*8)+4];
#pragma unroll
      for (int i = 0; i < 8; ++i)
#pragma unroll
        for (int j = 0; j < 8; ++j) acc[i][j] = fmaf(a[i], bb[j], acc[i][j]);
    }
  }

#pragma unroll
  for (int i = 0; i < 8; ++i) {
    int m = m0 + ty*8 + i;
    float bv = bias[m];
    float* dst = Y + ((size_t)b * M + m) * NS_ + n0 + tx*8;
    float4 r0 = make_float4(acc[i][0]+bv, acc[i][1]+bv, acc[i][2]+bv, acc[i][3]+bv);
    float4 r1 = make_float4(acc[i][4]+bv, acc[i][5]+bv, acc[i][6]+bv, acc[i][7]+bv);
    if (res) {
      const float* rsrc = res + ((size_t)b * M + m) * NS_ + n0 + tx*8;
      float4 e0 = *(const float4*)(rsrc);
      float4 e1 = *(const float4*)(rsrc + 4);
      r0.x += e0.x; r0.y += e0.y; r0.z += e0.z; r0.w += e0.w;
      r1.x += e1.x; r1.y += e1.y; r1.z += e1.z; r1.w += e1.w;
    }
    *(float4*)(dst)   = r0;
    *(float4*)(dst+4) = r1;
  }
}

// ---------------------------------------------------------------------------
// Fused: depthwise 5x5 conv (+bias) -> LN over CG channels -> tanh-GELU
//        -> 2-channel offset projection -> clip(+grid) -> bilinear gather of x2
// one thread per spatial position (64 positions / block), loop channels
// ---------------------------------------------------------------------------
__device__ __forceinline__ float gelu_t(float v) {
  float v3 = v*v*v;
  return 0.5f*v*(1.f + tanhf(0.7978845608028654f*(v + 0.044715f*v3)));
}

__global__ __launch_bounds__(64) void offset_sample(
    const float* __restrict__ q,      // (BG, CG, NS_) == (B, C, NS_)
    const float* __restrict__ x2,     // (BG, CG, NS_)
    const float* __restrict__ dw,     // (CG, 25)
    const float* __restrict__ dwb,    // (CG)
    const float* __restrict__ lng,    // (CG)
    const float* __restrict__ lnb,    // (CG)
    const float* __restrict__ offw,   // (2, CG)
    float* __restrict__ samp)         // (BG, CG, NS_)
{
  __shared__ float ts[CG_][64];       // 32 KB
  int bg   = blockIdx.x;              // 0..23
  int tile = blockIdx.y;              // 0..15
  int t = threadIdx.x;                // 0..63
  int n = tile*64 + t;
  int y = n >> 5, x = n & 31;

  const float* qb = q + (size_t)bg * CG_ * NS_;
  float sum = 0.f, sumsq = 0.f;

  for (int c = 0; c < CG_; ++c) {
    float acc = dwb[c];
    const float* qc = qb + (size_t)c * NS_;
    const float* wc = dw + c*25;
#pragma unroll
    for (int dy = -2; dy <= 2; ++dy) {
      int yy = y + dy;
      if (yy < 0 || yy > 31) continue;
      const float* row = qc + yy*32;
      const float* wrow = wc + (dy+2)*5;
#pragma unroll
      for (int dx = -2; dx <= 2; ++dx) {
        int xx = x + dx;
        if (xx >= 0 && xx <= 31) acc = fmaf(row[xx], wrow[dx+2], acc);
      }
    }
    ts[c][t] = acc;
    sum += acc; sumsq += acc*acc;
  }

  float mu  = sum * (1.f/CG_);
  float var = sumsq * (1.f/CG_) - mu*mu;
  float rs  = rsqrtf(var + EPS_);

  float off0 = 0.f, off1 = 0.f;
  for (int c = 0; c < CG_; ++c) {
    float vz = (ts[c][t] - mu) * rs * lng[c] + lnb[c];
    float g = gelu_t(vz);
    off0 = fmaf(offw[c], g, off0);
    off1 = fmaf(offw[CG_ + c], g, off1);
  }

  float gx = (x + 0.5f) * (2.f/32.f) - 1.f;
  float gy = (y + 0.5f) * (2.f/32.f) - 1.f;
  float px = fminf(fmaxf(off0 + gx, -1.f), 1.f);
  float py = fminf(fmaxf(off1 + gy, -1.f), 1.f);
  float ix = (px + 1.f) * 0.5f * 31.f;
  float iy = (py + 1.f) * 0.5f * 31.f;
  float x0f = floorf(ix), y0f = floorf(iy);
  float wx = ix - x0f,  wy = iy - y0f;
  int x0 = min(max((int)x0f, 0), 31), x1i = min(x0 + 1, 31);
  int y0 = min(max((int)y0f, 0), 31), y1i = min(y0 + 1, 31);
  int i00 = y0*32 + x0,  i01 = y0*32 + x1i;
  int i10 = y1i*32 + x0, i11 = y1i*32 + x1i;
  float w00 = (1.f-wx)*(1.f-wy), w01 = wx*(1.f-wy);
  float w10 = (1.f-wx)*wy,       w11 = wx*wy;

  const float* xb = x2 + (size_t)bg * CG_ * NS_;
  float* sb = samp + (size_t)bg * CG_ * NS_;
  for (int c = 0; c < CG_; ++c) {
    const float* xc = xb + (size_t)c * NS_;
    float v = w00*xc[i00] + w01*xc[i01] + w10*xc[i10] + w11*xc[i11];
    sb[(size_t)c * NS_ + n] = v;
  }
}

// ---------------------------------------------------------------------------
// Flash attention fp32: one (b,h) per 2 blocks; 2 queries per thread.
// K/V tile (64 keys) staged transposed in LDS as [key][d] so each key's
// 32-float column is 8 contiguous float4 broadcast reads.
// ---------------------------------------------------------------------------
__global__ __launch_bounds__(256) void attn_flash(
    const float* __restrict__ Q, const float* __restrict__ Kb,
    const float* __restrict__ Vb, float* __restrict__ O)
{
  __shared__ float Ks[64][36];
  __shared__ float Vs[64][36];
  const float scale = 0.17677669529663687f;   // 1/sqrt(32)

  int bh   = blockIdx.x >> 1;
  int half = blockIdx.x & 1;
  int b = bh / HEADS_, h = bh % HEADS_;
  size_t base = ((size_t)(b * C_ + h * HD_)) * NS_;
  const float* Qh = Q  + base;
  const float* Kh = Kb + base;
  const float* Vh = Vb + base;

  int t = threadIdx.x;
  int n0 = half*512 + t;
  int n1 = n0 + 256;

  float q0[HD_], q1[HD_], o0[HD_], o1[HD_];
#pragma unroll
  for (int d = 0; d < HD_; ++d) {
    q0[d] = Qh[(size_t)d*NS_ + n0] * scale;
    q1[d] = Qh[(size_t)d*NS_ + n1] * scale;
    o0[d] = 0.f; o1[d] = 0.f;
  }
  float m0 = -1e30f, l0 = 0.f, m1 = -1e30f, l1 = 0.f;

  for (int kt = 0; kt < NS_; kt += 64) {
    __syncthreads();
#pragma unroll
    for (int u = 0; u < 8; ++u) {
      int i = t + u*256;
      int d = i >> 6, kk = i & 63;
      Ks[kk][d] = Kh[(size_t)d*NS_ + kt + kk];
      Vs[kk][d] = Vh[(size_t)d*NS_ + kt + kk];
    }
    __syncthreads();

#pragma unroll 2
    for (int kk = 0; kk < 64; ++kk) {
      float s0 = 0.f, s1 = 0.f;
#pragma unroll
      for (int r = 0; r < HD_/4; ++r) {
        float4 kv = *(const float4*)&Ks[kk][r*4];
        s0 += q0[r*4+0]*kv.x + q0[r*4+1]*kv.y + q0[r*4+2]*kv.z + q0[r*4+3]*kv.w;
        s1 += q1[r*4+0]*kv.x + q1[r*4+1]*kv.y + q1[r*4+2]*kv.z + q1[r*4+3]*kv.w;
      }
      float vv[HD_];
#pragma unroll
      for (int r = 0; r < HD_/4; ++r) {
        float4 v4 = *(const float4*)&Vs[kk][r*4];
        vv[r*4+0] = v4.x; vv[r*4+1] = v4.y; vv[r*4+2] = v4.z; vv[r*4+3] = v4.w;
      }
      // query 0 online-softmax update (deferred rescale)
      if (s0 <= m0) {
        float p = __expf(s0 - m0);
        l0 += p;
#pragma unroll
        for (int d = 0; d < HD_; ++d) o0[d] = fmaf(p, vv[d], o0[d]);
      } else {
        float cc = __expf(m0 - s0);
        m0 = s0; l0 = l0*cc + 1.f;
#pragma unroll
        for (int d = 0; d < HD_; ++d) o0[d] = fmaf(o0[d], cc, vv[d]);
      }
      // query 1
      if (s1 <= m1) {
        float p = __expf(s1 - m1);
        l1 += p;
#pragma unroll
        for (int d = 0; d < HD_; ++d) o1[d] = fmaf(p, vv[d], o1[d]);
      } else {
        float cc = __expf(m1 - s1);
        m1 = s1; l1 = l1*cc + 1.f;
#pragma unroll
        for (int d = 0; d < HD_; ++d) o1[d] = fmaf(o1[d], cc, vv[d]);
      }
    }
  }

  float r0 = 1.f/l0, r1 = 1.f/l1;
  float* Oh = O + base;
#pragma unroll
  for (int d = 0; d < HD_; ++d) {
    Oh[(size_t)d*NS_ + n0] = o0[d]*r0;
    Oh[(size_t)d*NS_ + n1] = o1[d]*r1;
  }
}

// ---------------------------------------------------------------------------
extern "C" void kernel_launch(void* const* d_in, const int* in_sizes, int n_in,
                              void* d_out, int out_size, void* d_ws, size_t ws_size,
                              hipStream_t stream) {
  const float* x1      = (const float*)d_in[0];
  const float* x2      = (const float*)d_in[1];
  const float* Wq      = (const float*)d_in[2];
  const float* bq      = (const float*)d_in[3];
  const float* Wk      = (const float*)d_in[4];
  const float* bk      = (const float*)d_in[5];
  const float* Wv      = (const float*)d_in[6];
  const float* bv      = (const float*)d_in[7];
  const float* Wo      = (const float*)d_in[8];
  const float* bo      = (const float*)d_in[9];
  const float* off_dw  = (const float*)d_in[10];
  const float* off_dwb = (const float*)d_in[11];
  const float* ln_g    = (const float*)d_in[12];
  const float* ln_b    = (const float*)d_in[13];
  const float* off_w   = (const float*)d_in[14];
  float* out = (float*)d_out;
  float* ws  = (float*)d_ws;

  const size_t SZ = (size_t)B_ * C_ * NS_;   // 3,145,728 floats
  float* qb    = ws;
  float* sampb = ws + SZ;
  float* kb    = ws + 2*SZ;
  float* vb    = ws + 3*SZ;
  float* aob   = ws + 4*SZ;

  dim3 gg(NS_/TN, C_/TM, B_);   // (8, 6, 8)

  // q = Wq @ x1 + bq
  gemm_bcn<<<gg, 128, 0, stream>>>(x1, Wq, bq, nullptr, qb, C_, C_);
  // depthwise conv + LN + GELU + offsets + bilinear sample
  offset_sample<<<dim3(B_*GROUPS_, NS_/64), 64, 0, stream>>>(
      qb, x2, off_dw, off_dwb, ln_g, ln_b, off_w, sampb);
  // k, v projections
  gemm_bcn<<<gg, 128, 0, stream>>>(sampb, Wk, bk, nullptr, kb, C_, C_);
  gemm_bcn<<<gg, 128, 0, stream>>>(sampb, Wv, bv, nullptr, vb, C_, C_);
  // attention
  attn_flash<<<dim3(B_*HEADS_*2), 256, 0, stream>>>(qb, kb, vb, aob);
  // y = Wo @ attn_out + bo + x1
  gemm_bcn<<<gg, 128, 0, stream>>>(aob, Wo, bo, x1, out, C_, C_);
}

// Round 2
// 254.996 us; speedup vs baseline: 4.0490x; 4.0490x over previous
//
#include <hip/hip_runtime.h>
#include <math.h>

#define B_  8
#define C_  384
#define NS_ 1024
#define HEADS_ 12
#define HD_ 32
#define GROUPS_ 3
#define CG_ 128
#define EPS_ 1e-5f
#define QSCALE 0.17677669529663687f

typedef __attribute__((ext_vector_type(8))) short bf16x8;
typedef __attribute__((ext_vector_type(4))) short bf16x4;
typedef __attribute__((ext_vector_type(4))) float f32x4;
typedef __attribute__((ext_vector_type(8))) __bf16 b8;

static __device__ __forceinline__ short f2b(float f) {
  union { float f; unsigned u; } v; v.f = f;
  unsigned r = v.u + 0x7fffu + ((v.u >> 16) & 1u);   // RNE
  return (short)(r >> 16);
}

static __device__ __forceinline__ f32x4 MFMA(bf16x8 a, bf16x8 b, f32x4 c) {
  return __builtin_amdgcn_mfma_f32_16x16x32_bf16(
      __builtin_bit_cast(b8, a), __builtin_bit_cast(b8, b), c, 0, 0, 0);
}

// ---------------------------------------------------------------------------
// weight fp32 -> bf16 (4 matrices)
// ---------------------------------------------------------------------------
__global__ void convw(const float* __restrict__ s0, const float* __restrict__ s1,
                      const float* __restrict__ s2, const float* __restrict__ s3,
                      short* __restrict__ d0, short* __restrict__ d1,
                      short* __restrict__ d2, short* __restrict__ d3, int n) {
  int i = blockIdx.x * 256 + threadIdx.x;
  if (i >= n) return;
  const float* s = blockIdx.y == 0 ? s0 : blockIdx.y == 1 ? s1 : blockIdx.y == 2 ? s2 : s3;
  short*       d = blockIdx.y == 0 ? d0 : blockIdx.y == 1 ? d1 : blockIdx.y == 2 ? d2 : d3;
  d[i] = f2b(s[i]);
}

// ---------------------------------------------------------------------------
// x1 (B,C,NS) f32 -> x1t (B,NS,C) bf16
// ---------------------------------------------------------------------------
__global__ __launch_bounds__(256) void transp(const float* __restrict__ src,
                                              short* __restrict__ dst) {
  __shared__ float tl[32][33];
  int n0 = blockIdx.x * 32, c0 = blockIdx.y * 32, b = blockIdx.z;
  int tx = threadIdx.x & 31, ty = threadIdx.x >> 5;   // ty 0..7
#pragma unroll
  for (int i = 0; i < 4; ++i)
    tl[ty + 8 * i][tx] = src[((size_t)b * C_ + c0 + ty + 8 * i) * NS_ + n0 + tx];
  __syncthreads();
#pragma unroll
  for (int i = 0; i < 4; ++i)
    dst[((size_t)b * NS_ + n0 + ty + 8 * i) * C_ + c0 + tx] = f2b(tl[tx][ty + 8 * i]);
}

// ---------------------------------------------------------------------------
// MFMA GEMM, n-major activations: Y[b][n][m] = sum_k A[b][n][k] * W[m][k] + bias
// A bf16 (B,NS,C), W bf16 (M=384,K=384). 128x128 tile, 4 waves, no LDS.
// MODE 0: out n-major bf16            (k projection)
// MODE 1: outf d-major f32, outb n-major bf16 * QSCALE   (q projection)
// MODE 2: out d-major bf16            (v projection)
// MODE 3: outf d-major f32 + res      (final projection + residual)
// ---------------------------------------------------------------------------
template <int MODE>
__global__ __launch_bounds__(256) void gemm_nm(
    const short* __restrict__ A, const short* __restrict__ Wb,
    const float* __restrict__ bias, const float* __restrict__ res,
    short* __restrict__ outb, float* __restrict__ outf) {
  int b = blockIdx.z;
  int n0 = blockIdx.x * 128;
  int m0 = blockIdx.y * 128;
  int wv = threadIdx.x >> 6;
  int lane = threadIdx.x & 63;
  int g = lane >> 4, r15 = lane & 15;
  int wr = (wv >> 1) * 64, wc = (wv & 1) * 64;

  const short* Ab = A + (size_t)b * NS_ * C_;
  f32x4 acc[4][4];
#pragma unroll
  for (int i = 0; i < 4; ++i)
#pragma unroll
    for (int j = 0; j < 4; ++j) acc[i][j] = (f32x4){0.f, 0.f, 0.f, 0.f};

  for (int kc = 0; kc < C_; kc += 32) {
    bf16x8 af[4], bfr[4];
#pragma unroll
    for (int rt = 0; rt < 4; ++rt)
      af[rt] = *(const bf16x8*)(Ab + (size_t)(n0 + wr + rt * 16 + r15) * C_ + kc + g * 8);
#pragma unroll
    for (int ct = 0; ct < 4; ++ct)
      bfr[ct] = *(const bf16x8*)(Wb + (size_t)(m0 + wc + ct * 16 + r15) * C_ + kc + g * 8);
#pragma unroll
    for (int rt = 0; rt < 4; ++rt)
#pragma unroll
      for (int ct = 0; ct < 4; ++ct) acc[rt][ct] = MFMA(af[rt], bfr[ct], acc[rt][ct]);
  }

#pragma unroll
  for (int rt = 0; rt < 4; ++rt)
#pragma unroll
    for (int ct = 0; ct < 4; ++ct) {
      int m = m0 + wc + ct * 16 + r15;
      int nb = n0 + wr + rt * 16 + g * 4;
      float bv = bias[m];
      f32x4 v = acc[rt][ct];
      v.x += bv; v.y += bv; v.z += bv; v.w += bv;
      if (MODE == 1) {
        *(f32x4*)(outf + ((size_t)b * C_ + m) * NS_ + nb) = v;
        outb[((size_t)b * NS_ + nb + 0) * C_ + m] = f2b(v.x * QSCALE);
        outb[((size_t)b * NS_ + nb + 1) * C_ + m] = f2b(v.y * QSCALE);
        outb[((size_t)b * NS_ + nb + 2) * C_ + m] = f2b(v.z * QSCALE);
        outb[((size_t)b * NS_ + nb + 3) * C_ + m] = f2b(v.w * QSCALE);
      } else if (MODE == 0) {
        outb[((size_t)b * NS_ + nb + 0) * C_ + m] = f2b(v.x);
        outb[((size_t)b * NS_ + nb + 1) * C_ + m] = f2b(v.y);
        outb[((size_t)b * NS_ + nb + 2) * C_ + m] = f2b(v.z);
        outb[((size_t)b * NS_ + nb + 3) * C_ + m] = f2b(v.w);
      } else if (MODE == 2) {
        bf16x4 s4 = {f2b(v.x), f2b(v.y), f2b(v.z), f2b(v.w)};
        *(bf16x4*)(outb + ((size_t)b * C_ + m) * NS_ + nb) = s4;
      } else {
        const f32x4 rv = *(const f32x4*)(res + ((size_t)b * C_ + m) * NS_ + nb);
        v.x += rv.x; v.y += rv.y; v.z += rv.z; v.w += rv.w;
        *(f32x4*)(outf + ((size_t)b * C_ + m) * NS_ + nb) = v;
      }
    }
}

// ---------------------------------------------------------------------------
// fused depthwise 5x5 + LN + GELU + offset proj + bilinear sample
// block: 4 c-chunk waves x 64 positions; out samp n-major bf16
// ---------------------------------------------------------------------------
__global__ __launch_bounds__(256) void offsample2(
    const float* __restrict__ qd, const float* __restrict__ x2,
    const float* __restrict__ dw, const float* __restrict__ dwb,
    const float* __restrict__ lng, const float* __restrict__ lnb,
    const float* __restrict__ offw, short* __restrict__ samp) {
  __shared__ float ts[CG_][65];
  __shared__ float red[4][4][64];
  int bg = blockIdx.x, tile = blockIdx.y;
  int cc = threadIdx.x >> 6, t = threadIdx.x & 63;
  int n = tile * 64 + t, y = n >> 5, x = n & 31;
  const float* qb = qd + (size_t)bg * CG_ * NS_;

  float s = 0.f, ss = 0.f;
  for (int c = cc * 32; c < cc * 32 + 32; ++c) {
    float acc = dwb[c];
    const float* qc = qb + (size_t)c * NS_;
    const float* wc = dw + c * 25;
#pragma unroll
    for (int dy = -2; dy <= 2; ++dy) {
      int yy = y + dy;
      if (yy < 0 || yy > 31) continue;
      const float* row = qc + yy * 32;
      const float* wr_ = wc + (dy + 2) * 5;
#pragma unroll
      for (int dx = -2; dx <= 2; ++dx) {
        int xx = x + dx;
        if (xx >= 0 && xx <= 31) acc = fmaf(row[xx], wr_[dx + 2], acc);
      }
    }
    ts[c][t] = acc; s += acc; ss += acc * acc;
  }
  red[0][cc][t] = s; red[1][cc][t] = ss;
  __syncthreads();
  float S  = red[0][0][t] + red[0][1][t] + red[0][2][t] + red[0][3][t];
  float SS = red[1][0][t] + red[1][1][t] + red[1][2][t] + red[1][3][t];
  float mu = S * (1.f / CG_);
  float var = SS * (1.f / CG_) - mu * mu;
  float rs = rsqrtf(var + EPS_);

  float o0 = 0.f, o1 = 0.f;
  for (int c = cc * 32; c < cc * 32 + 32; ++c) {
    float z = (ts[c][t] - mu) * rs * lng[c] + lnb[c];
    float z3 = z * z * z;
    float ge = 0.5f * z * (1.f + tanhf(0.7978845608028654f * (z + 0.044715f * z3)));
    o0 = fmaf(offw[c], ge, o0);
    o1 = fmaf(offw[CG_ + c], ge, o1);
  }
  red[2][cc][t] = o0; red[3][cc][t] = o1;
  __syncthreads();
  float off0 = red[2][0][t] + red[2][1][t] + red[2][2][t] + red[2][3][t];
  float off1 = red[3][0][t] + red[3][1][t] + red[3][2][t] + red[3][3][t];

  float gx = (x + 0.5f) * (2.f / 32.f) - 1.f;
  float gy = (y + 0.5f) * (2.f / 32.f) - 1.f;
  float px = fminf(fmaxf(off0 + gx, -1.f), 1.f);
  float py = fminf(fmaxf(off1 + gy, -1.f), 1.f);
  float ix = (px + 1.f) * 0.5f * 31.f;
  float iy = (py + 1.f) * 0.5f * 31.f;
  float x0f = floorf(ix), y0f = floorf(iy);
  float wx = ix - x0f, wy = iy - y0f;
  int x0 = min(max((int)x0f, 0), 31), x1i = min(x0 + 1, 31);
  int y0 = min(max((int)y0f, 0), 31), y1i = min(y0 + 1, 31);
  int i00 = y0 * 32 + x0,  i01 = y0 * 32 + x1i;
  int i10 = y1i * 32 + x0, i11 = y1i * 32 + x1i;
  float w00 = (1.f - wx) * (1.f - wy), w01 = wx * (1.f - wy);
  float w10 = (1.f - wx) * wy,         w11 = wx * wy;

  int b = bg / GROUPS_, gi = bg % GROUPS_;
  const float* xb = x2 + (size_t)bg * CG_ * NS_;
  short* sp = samp + ((size_t)b * NS_ + n) * C_ + gi * CG_;
  for (int c = cc * 32; c < cc * 32 + 32; ++c) {
    const float* xc = xb + (size_t)c * NS_;
    float v = w00 * xc[i00] + w01 * xc[i01] + w10 * xc[i10] + w11 * xc[i11];
    sp[c] = f2b(v);
  }
}

// ---------------------------------------------------------------------------
// MFMA flash attention. wave = 32 queries; swapped QK^T (S^T = mfma(K,Q)) so
// the S^T accumulator feeds PV's B-operand directly via the per-lane-group
// key permutation sigma(8g+jj) = k0 + (jj<4 ? 4g+jj : 16+4g+jj-4).
// q_nC (B,NS,C) bf16 prescaled; k_nC (B,NS,C) bf16; v_dN (B,C,NS) bf16.
// out o_nC (B,NS,C) bf16.
// ---------------------------------------------------------------------------
__global__ __launch_bounds__(256) void attn_mfma(
    const short* __restrict__ qn, const short* __restrict__ kn,
    const short* __restrict__ vd, short* __restrict__ on) {
  int bh = blockIdx.y, b = bh / HEADS_, h = bh % HEADS_;
  int wv = threadIdx.x >> 6, lane = threadIdx.x & 63;
  int g = lane >> 4, q15 = lane & 15;
  int q0 = blockIdx.x * 128 + wv * 32;

  const short* Qb = qn + (size_t)b * NS_ * C_ + h * HD_;
  const short* Kb = kn + (size_t)b * NS_ * C_ + h * HD_;
  const short* Vb = vd + ((size_t)b * C_ + h * HD_) * NS_;

  bf16x8 qf[2];
  qf[0] = *(const bf16x8*)(Qb + (size_t)(q0 + q15) * C_ + g * 8);
  qf[1] = *(const bf16x8*)(Qb + (size_t)(q0 + 16 + q15) * C_ + g * 8);

  f32x4 o[2][2];
  o[0][0] = o[0][1] = o[1][0] = o[1][1] = (f32x4){0.f, 0.f, 0.f, 0.f};
  float m[2] = {-1e30f, -1e30f}, l[2] = {0.f, 0.f};

  for (int k0 = 0; k0 < NS_; k0 += 32) {
    bf16x8 kf0 = *(const bf16x8*)(Kb + (size_t)(k0 + q15) * C_ + g * 8);
    bf16x8 kf1 = *(const bf16x8*)(Kb + (size_t)(k0 + 16 + q15) * C_ + g * 8);
    bf16x8 vf[2];
#pragma unroll
    for (int dt = 0; dt < 2; ++dt) {
      const short* vp = Vb + (size_t)(dt * 16 + q15) * NS_ + k0 + g * 4;
      bf16x4 lo = *(const bf16x4*)(vp);
      bf16x4 hi = *(const bf16x4*)(vp + 16);
      vf[dt] = (bf16x8){lo.x, lo.y, lo.z, lo.w, hi.x, hi.y, hi.z, hi.w};
    }
#pragma unroll
    for (int qt = 0; qt < 2; ++qt) {
      f32x4 z = {0.f, 0.f, 0.f, 0.f};
      f32x4 t0 = MFMA(kf0, qf[qt], z);   // S^T rows k0+4g+r, col q15
      f32x4 t1 = MFMA(kf1, qf[qt], z);   // S^T rows k0+16+4g+r
      float cm = fmaxf(fmaxf(fmaxf(t0.x, t0.y), fmaxf(t0.z, t0.w)),
                       fmaxf(fmaxf(t1.x, t1.y), fmaxf(t1.z, t1.w)));
      cm = fmaxf(cm, __shfl_xor(cm, 16));
      cm = fmaxf(cm, __shfl_xor(cm, 32));
      float mn = fmaxf(m[qt], cm);
      float fac = __expf(m[qt] - mn);
      m[qt] = mn;
      float p0 = __expf(t0.x - mn), p1 = __expf(t0.y - mn);
      float p2 = __expf(t0.z - mn), p3 = __expf(t0.w - mn);
      float p4 = __expf(t1.x - mn), p5 = __expf(t1.y - mn);
      float p6 = __expf(t1.z - mn), p7 = __expf(t1.w - mn);
      l[qt] = l[qt] * fac + (((p0 + p1) + (p2 + p3)) + ((p4 + p5) + (p6 + p7)));
      o[qt][0] *= fac;
      o[qt][1] *= fac;
      bf16x8 pf = (bf16x8){f2b(p0), f2b(p1), f2b(p2), f2b(p3),
                           f2b(p4), f2b(p5), f2b(p6), f2b(p7)};
      o[qt][0] = MFMA(vf[0], pf, o[qt][0]);
      o[qt][1] = MFMA(vf[1], pf, o[qt][1]);
    }
  }

#pragma unroll
  for (int qt = 0; qt < 2; ++qt) {
    float lt = l[qt];
    lt += __shfl_xor(lt, 16);
    lt += __shfl_xor(lt, 32);
    float rl = 1.f / lt;
#pragma unroll
    for (int dt = 0; dt < 2; ++dt) {
      f32x4 ov = o[qt][dt];
      bf16x4 s4 = {f2b(ov.x * rl), f2b(ov.y * rl), f2b(ov.z * rl), f2b(ov.w * rl)};
      *(bf16x4*)(on + ((size_t)b * NS_ + q0 + qt * 16 + q15) * C_ + h * HD_ + dt * 16 + g * 4) = s4;
    }
  }
}

// ---------------------------------------------------------------------------
extern "C" void kernel_launch(void* const* d_in, const int* in_sizes, int n_in,
                              void* d_out, int out_size, void* d_ws, size_t ws_size,
                              hipStream_t stream) {
  const float* x1      = (const float*)d_in[0];
  const float* x2      = (const float*)d_in[1];
  const float* Wq      = (const float*)d_in[2];
  const float* bq      = (const float*)d_in[3];
  const float* Wk      = (const float*)d_in[4];
  const float* bk      = (const float*)d_in[5];
  const float* Wv      = (const float*)d_in[6];
  const float* bv      = (const float*)d_in[7];
  const float* Wo      = (const float*)d_in[8];
  const float* bo      = (const float*)d_in[9];
  const float* off_dw  = (const float*)d_in[10];
  const float* off_dwb = (const float*)d_in[11];
  const float* ln_g    = (const float*)d_in[12];
  const float* ln_b    = (const float*)d_in[13];
  const float* off_w   = (const float*)d_in[14];

  char* base = (char*)d_ws;
  const size_t SZ = (size_t)B_ * C_ * NS_;
  float* q_dC = (float*)base;                   // SZ f32
  short* q_nC = (short*)(base + SZ * 4);        // SZ bf16
  short* samp = (short*)(base + SZ * 6);
  short* k_nC = (short*)(base + SZ * 8);
  short* v_dN = (short*)(base + SZ * 10);
  short* o_nC = (short*)(base + SZ * 12);
  short* x1t  = (short*)(base + SZ * 14);
  short* Wqb  = (short*)(base + SZ * 16);
  short* Wkb  = Wqb + C_ * C_;
  short* Wvb  = Wkb + C_ * C_;
  short* Wob  = Wvb + C_ * C_;

  convw<<<dim3((C_ * C_ + 255) / 256, 4), 256, 0, stream>>>(
      Wq, Wk, Wv, Wo, Wqb, Wkb, Wvb, Wob, C_ * C_);
  transp<<<dim3(NS_ / 32, C_ / 32, B_), 256, 0, stream>>>(x1, x1t);
  gemm_nm<1><<<dim3(8, 3, B_), 256, 0, stream>>>(x1t, Wqb, bq, nullptr, q_nC, q_dC);
  offsample2<<<dim3(B_ * GROUPS_, NS_ / 64), 256, 0, stream>>>(
      q_dC, x2, off_dw, off_dwb, ln_g, ln_b, off_w, samp);
  gemm_nm<0><<<dim3(8, 3, B_), 256, 0, stream>>>(samp, Wkb, bk, nullptr, k_nC, nullptr);
  gemm_nm<2><<<dim3(8, 3, B_), 256, 0, stream>>>(samp, Wvb, bv, nullptr, v_dN, nullptr);
  attn_mfma<<<dim3(NS_ / 128, B_ * HEADS_), 256, 0, stream>>>(q_nC, k_nC, v_dN, o_nC);
  gemm_nm<3><<<dim3(8, 3, B_), 256, 0, stream>>>(o_nC, Wob, bo, x1, nullptr, (float*)d_out);
}

// Round 3
// 190.201 us; speedup vs baseline: 5.4284x; 1.3407x over previous
//
#include <hip/hip_runtime.h>
#include <math.h>

#define B_  8
#define C_  384
#define NS_ 1024
#define HEADS_ 12
#define HD_ 32
#define GROUPS_ 3
#define CG_ 128
#define EPS_ 1e-5f
#define QSCALE 0.17677669529663687f

typedef __attribute__((ext_vector_type(8))) short bf16x8;
typedef __attribute__((ext_vector_type(4))) short bf16x4;
typedef __attribute__((ext_vector_type(4))) float f32x4;
typedef __attribute__((ext_vector_type(8))) __bf16 b8;

static __device__ __forceinline__ short f2b(float f) {
  union { float f; unsigned u; } v; v.f = f;
  unsigned r = v.u + 0x7fffu + ((v.u >> 16) & 1u);   // RNE
  return (short)(r >> 16);
}

static __device__ __forceinline__ f32x4 MFMA(bf16x8 a, bf16x8 b, f32x4 c) {
  return __builtin_amdgcn_mfma_f32_16x16x32_bf16(
      __builtin_bit_cast(b8, a), __builtin_bit_cast(b8, b), c, 0, 0, 0);
}

// ---------------------------------------------------------------------------
// weight fp32 -> bf16 (4 matrices)
// ---------------------------------------------------------------------------
__global__ void convw(const float* __restrict__ s0, const float* __restrict__ s1,
                      const float* __restrict__ s2, const float* __restrict__ s3,
                      short* __restrict__ d0, short* __restrict__ d1,
                      short* __restrict__ d2, short* __restrict__ d3, int n) {
  int i = blockIdx.x * 256 + threadIdx.x;
  if (i >= n) return;
  const float* s = blockIdx.y == 0 ? s0 : blockIdx.y == 1 ? s1 : blockIdx.y == 2 ? s2 : s3;
  short*       d = blockIdx.y == 0 ? d0 : blockIdx.y == 1 ? d1 : blockIdx.y == 2 ? d2 : d3;
  d[i] = f2b(s[i]);
}

// ---------------------------------------------------------------------------
// x1 (B,C,NS) f32 -> x1t (B,NS,C) bf16
// ---------------------------------------------------------------------------
__global__ __launch_bounds__(256) void transp(const float* __restrict__ src,
                                              short* __restrict__ dst) {
  __shared__ float tl[32][33];
  int n0 = blockIdx.x * 32, c0 = blockIdx.y * 32, b = blockIdx.z;
  int tx = threadIdx.x & 31, ty = threadIdx.x >> 5;   // ty 0..7
#pragma unroll
  for (int i = 0; i < 4; ++i)
    tl[ty + 8 * i][tx] = src[((size_t)b * C_ + c0 + ty + 8 * i) * NS_ + n0 + tx];
  __syncthreads();
#pragma unroll
  for (int i = 0; i < 4; ++i)
    dst[((size_t)b * NS_ + n0 + ty + 8 * i) * C_ + c0 + tx] = f2b(tl[tx][ty + 8 * i]);
}

// ---------------------------------------------------------------------------
// MFMA GEMM, n-major activations: Y[b][n][m] = sum_k A[b][n][k] * W[m][k] + bias
// MODE 0: out n-major bf16            (k projection)
// MODE 1: outf d-major f32, outb n-major bf16 * QSCALE   (q projection)
// MODE 2: out d-major bf16            (v projection)
// MODE 3: outf d-major f32 + res      (final projection + residual)
// ---------------------------------------------------------------------------
template <int MODE>
__global__ __launch_bounds__(256) void gemm_nm(
    const short* __restrict__ A, const short* __restrict__ Wb,
    const float* __restrict__ bias, const float* __restrict__ res,
    short* __restrict__ outb, float* __restrict__ outf) {
  int b = blockIdx.z;
  int n0 = blockIdx.x * 128;
  int m0 = blockIdx.y * 128;
  int wv = threadIdx.x >> 6;
  int lane = threadIdx.x & 63;
  int g = lane >> 4, r15 = lane & 15;
  int wr = (wv >> 1) * 64, wc = (wv & 1) * 64;

  const short* Ab = A + (size_t)b * NS_ * C_;
  f32x4 acc[4][4];
#pragma unroll
  for (int i = 0; i < 4; ++i)
#pragma unroll
    for (int j = 0; j < 4; ++j) acc[i][j] = (f32x4){0.f, 0.f, 0.f, 0.f};

  for (int kc = 0; kc < C_; kc += 32) {
    bf16x8 af[4], bfr[4];
#pragma unroll
    for (int rt = 0; rt < 4; ++rt)
      af[rt] = *(const bf16x8*)(Ab + (size_t)(n0 + wr + rt * 16 + r15) * C_ + kc + g * 8);
#pragma unroll
    for (int ct = 0; ct < 4; ++ct)
      bfr[ct] = *(const bf16x8*)(Wb + (size_t)(m0 + wc + ct * 16 + r15) * C_ + kc + g * 8);
#pragma unroll
    for (int rt = 0; rt < 4; ++rt)
#pragma unroll
      for (int ct = 0; ct < 4; ++ct) acc[rt][ct] = MFMA(af[rt], bfr[ct], acc[rt][ct]);
  }

#pragma unroll
  for (int rt = 0; rt < 4; ++rt)
#pragma unroll
    for (int ct = 0; ct < 4; ++ct) {
      int m = m0 + wc + ct * 16 + r15;
      int nb = n0 + wr + rt * 16 + g * 4;
      float bv = bias[m];
      f32x4 v = acc[rt][ct];
      v.x += bv; v.y += bv; v.z += bv; v.w += bv;
      if (MODE == 1) {
        *(f32x4*)(outf + ((size_t)b * C_ + m) * NS_ + nb) = v;
        outb[((size_t)b * NS_ + nb + 0) * C_ + m] = f2b(v.x * QSCALE);
        outb[((size_t)b * NS_ + nb + 1) * C_ + m] = f2b(v.y * QSCALE);
        outb[((size_t)b * NS_ + nb + 2) * C_ + m] = f2b(v.z * QSCALE);
        outb[((size_t)b * NS_ + nb + 3) * C_ + m] = f2b(v.w * QSCALE);
      } else if (MODE == 0) {
        outb[((size_t)b * NS_ + nb + 0) * C_ + m] = f2b(v.x);
        outb[((size_t)b * NS_ + nb + 1) * C_ + m] = f2b(v.y);
        outb[((size_t)b * NS_ + nb + 2) * C_ + m] = f2b(v.z);
        outb[((size_t)b * NS_ + nb + 3) * C_ + m] = f2b(v.w);
      } else if (MODE == 2) {
        bf16x4 s4 = {f2b(v.x), f2b(v.y), f2b(v.z), f2b(v.w)};
        *(bf16x4*)(outb + ((size_t)b * C_ + m) * NS_ + nb) = s4;
      } else {
        const f32x4 rv = *(const f32x4*)(res + ((size_t)b * C_ + m) * NS_ + nb);
        v.x += rv.x; v.y += rv.y; v.z += rv.z; v.w += rv.w;
        *(f32x4*)(outf + ((size_t)b * C_ + m) * NS_ + nb) = v;
      }
    }
}

// ---------------------------------------------------------------------------
// fused depthwise 5x5 + LN + GELU + offset proj + bilinear sample, v3.
// block = (bg, 16-position half-row); 256 threads = (cc in [0,16)) x (p in [0,16))
// each thread: 8 channels, conv outputs in registers. grid 24x64 = 1536 blocks.
// ---------------------------------------------------------------------------
__global__ __launch_bounds__(256) void offsample3(
    const float* __restrict__ qd, const float* __restrict__ x2,
    const float* __restrict__ dw, const float* __restrict__ dwb,
    const float* __restrict__ lng, const float* __restrict__ lnb,
    const float* __restrict__ offw, short* __restrict__ samp) {
  __shared__ float redS[4][16], redSS[4][16], redO0[4][16], redO1[4][16];
  int bg = blockIdx.x, t16 = blockIdx.y;
  int tid = threadIdx.x;
  int cc = tid >> 4, p = tid & 15;
  int wv = tid >> 6, lane = tid & 63;
  int n = t16 * 16 + p;
  int y = t16 >> 1;                  // block-uniform row
  int x = ((t16 & 1) << 4) + p;
  int c0 = cc << 3;

  const float* qb = qd + (size_t)bg * CG_ * NS_;

  float a[8];
  float s = 0.f, ss = 0.f;
#pragma unroll 2
  for (int i = 0; i < 8; ++i) {
    int c = c0 + i;
    const float* qc = qb + (size_t)c * NS_;
    const float* wc = dw + c * 25;
    float acc = dwb[c];
#pragma unroll
    for (int dy = -2; dy <= 2; ++dy) {
      int yy = y + dy;
      if (yy < 0 || yy > 31) continue;            // scalar branch (y uniform)
      const float* row = qc + yy * 32;
      const float* wr_ = wc + (dy + 2) * 5;
#pragma unroll
      for (int dx = -2; dx <= 2; ++dx) {
        int xx = x + dx;
        int xcl = min(max(xx, 0), 31);
        float v = row[xcl];
        if (xx != xcl) v = 0.f;                   // predicated edge zero
        acc = fmaf(v, wr_[dx + 2], acc);
      }
    }
    a[i] = acc;
    s += acc; ss += acc * acc;
  }

  s  += __shfl_xor(s, 16);  s  += __shfl_xor(s, 32);
  ss += __shfl_xor(ss, 16); ss += __shfl_xor(ss, 32);
  if (lane < 16) { redS[wv][lane] = s; redSS[wv][lane] = ss; }
  __syncthreads();
  float S  = (redS[0][p]  + redS[1][p])  + (redS[2][p]  + redS[3][p]);
  float SS = (redSS[0][p] + redSS[1][p]) + (redSS[2][p] + redSS[3][p]);
  float mu = S * (1.f / CG_);
  float var = SS * (1.f / CG_) - mu * mu;
  float rs = rsqrtf(var + EPS_);

  float o0 = 0.f, o1 = 0.f;
#pragma unroll
  for (int i = 0; i < 8; ++i) {
    int c = c0 + i;
    float z = (a[i] - mu) * rs * lng[c] + lnb[c];
    // gelu(z) = z * sigmoid(1.5957691216*(z + 0.044715 z^3))  (== tanh form)
    float u = z * fmaf(0.044715f * z, z, 1.f);
    float e = __expf(-1.5957691216057308f * u);
    float ge = z * __builtin_amdgcn_rcpf(1.f + e);
    o0 = fmaf(offw[c], ge, o0);
    o1 = fmaf(offw[CG_ + c], ge, o1);
  }
  o0 += __shfl_xor(o0, 16); o0 += __shfl_xor(o0, 32);
  o1 += __shfl_xor(o1, 16); o1 += __shfl_xor(o1, 32);
  if (lane < 16) { redO0[wv][lane] = o0; redO1[wv][lane] = o1; }
  __syncthreads();
  float off0 = (redO0[0][p] + redO0[1][p]) + (redO0[2][p] + redO0[3][p]);
  float off1 = (redO1[0][p] + redO1[1][p]) + (redO1[2][p] + redO1[3][p]);

  float gx = (x + 0.5f) * 0.0625f - 1.f;
  float gy = (y + 0.5f) * 0.0625f - 1.f;
  float px = fminf(fmaxf(off0 + gx, -1.f), 1.f);
  float py = fminf(fmaxf(off1 + gy, -1.f), 1.f);
  float ix = (px + 1.f) * 0.5f * 31.f;
  float iy = (py + 1.f) * 0.5f * 31.f;
  float x0f = floorf(ix), y0f = floorf(iy);
  float wx = ix - x0f, wy = iy - y0f;
  int x0 = min(max((int)x0f, 0), 31), x1i = min(x0 + 1, 31);
  int y0 = min(max((int)y0f, 0), 31), y1i = min(y0 + 1, 31);
  int i00 = y0 * 32 + x0,  i01 = y0 * 32 + x1i;
  int i10 = y1i * 32 + x0, i11 = y1i * 32 + x1i;
  float w00 = (1.f - wx) * (1.f - wy), w01 = wx * (1.f - wy);
  float w10 = (1.f - wx) * wy,         w11 = wx * wy;

  int b = bg / GROUPS_, gi = bg % GROUPS_;
  const float* xb = x2 + (size_t)bg * CG_ * NS_;
  short out8[8];
#pragma unroll
  for (int i = 0; i < 8; ++i) {
    const float* xc = xb + (size_t)(c0 + i) * NS_;
    float v = w00 * xc[i00] + w01 * xc[i01] + w10 * xc[i10] + w11 * xc[i11];
    out8[i] = f2b(v);
  }
  *(bf16x8*)(samp + ((size_t)b * NS_ + n) * C_ + gi * CG_ + c0) = *(bf16x8*)out8;
}

// ---------------------------------------------------------------------------
// MFMA flash attention. wave = 32 queries; swapped QK^T (S^T = mfma(K,Q)).
// ---------------------------------------------------------------------------
__global__ __launch_bounds__(256) void attn_mfma(
    const short* __restrict__ qn, const short* __restrict__ kn,
    const short* __restrict__ vd, short* __restrict__ on) {
  int bh = blockIdx.y, b = bh / HEADS_, h = bh % HEADS_;
  int wv = threadIdx.x >> 6, lane = threadIdx.x & 63;
  int g = lane >> 4, q15 = lane & 15;
  int q0 = blockIdx.x * 128 + wv * 32;

  const short* Qb = qn + (size_t)b * NS_ * C_ + h * HD_;
  const short* Kb = kn + (size_t)b * NS_ * C_ + h * HD_;
  const short* Vb = vd + ((size_t)b * C_ + h * HD_) * NS_;

  bf16x8 qf[2];
  qf[0] = *(const bf16x8*)(Qb + (size_t)(q0 + q15) * C_ + g * 8);
  qf[1] = *(const bf16x8*)(Qb + (size_t)(q0 + 16 + q15) * C_ + g * 8);

  f32x4 o[2][2];
  o[0][0] = o[0][1] = o[1][0] = o[1][1] = (f32x4){0.f, 0.f, 0.f, 0.f};
  float m[2] = {-1e30f, -1e30f}, l[2] = {0.f, 0.f};

  for (int k0 = 0; k0 < NS_; k0 += 32) {
    bf16x8 kf0 = *(const bf16x8*)(Kb + (size_t)(k0 + q15) * C_ + g * 8);
    bf16x8 kf1 = *(const bf16x8*)(Kb + (size_t)(k0 + 16 + q15) * C_ + g * 8);
    bf16x8 vf[2];
#pragma unroll
    for (int dt = 0; dt < 2; ++dt) {
      const short* vp = Vb + (size_t)(dt * 16 + q15) * NS_ + k0 + g * 4;
      bf16x4 lo = *(const bf16x4*)(vp);
      bf16x4 hi = *(const bf16x4*)(vp + 16);
      vf[dt] = (bf16x8){lo.x, lo.y, lo.z, lo.w, hi.x, hi.y, hi.z, hi.w};
    }
#pragma unroll
    for (int qt = 0; qt < 2; ++qt) {
      f32x4 z = {0.f, 0.f, 0.f, 0.f};
      f32x4 t0 = MFMA(kf0, qf[qt], z);
      f32x4 t1 = MFMA(kf1, qf[qt], z);
      float cm = fmaxf(fmaxf(fmaxf(t0.x, t0.y), fmaxf(t0.z, t0.w)),
                       fmaxf(fmaxf(t1.x, t1.y), fmaxf(t1.z, t1.w)));
      cm = fmaxf(cm, __shfl_xor(cm, 16));
      cm = fmaxf(cm, __shfl_xor(cm, 32));
      float mn = fmaxf(m[qt], cm);
      float fac = __expf(m[qt] - mn);
      m[qt] = mn;
      float p0 = __expf(t0.x - mn), p1 = __expf(t0.y - mn);
      float p2 = __expf(t0.z - mn), p3 = __expf(t0.w - mn);
      float p4 = __expf(t1.x - mn), p5 = __expf(t1.y - mn);
      float p6 = __expf(t1.z - mn), p7 = __expf(t1.w - mn);
      l[qt] = l[qt] * fac + (((p0 + p1) + (p2 + p3)) + ((p4 + p5) + (p6 + p7)));
      o[qt][0] *= fac;
      o[qt][1] *= fac;
      bf16x8 pf = (bf16x8){f2b(p0), f2b(p1), f2b(p2), f2b(p3),
                           f2b(p4), f2b(p5), f2b(p6), f2b(p7)};
      o[qt][0] = MFMA(vf[0], pf, o[qt][0]);
      o[qt][1] = MFMA(vf[1], pf, o[qt][1]);
    }
  }

#pragma unroll
  for (int qt = 0; qt < 2; ++qt) {
    float lt = l[qt];
    lt += __shfl_xor(lt, 16);
    lt += __shfl_xor(lt, 32);
    float rl = 1.f / lt;
#pragma unroll
    for (int dt = 0; dt < 2; ++dt) {
      f32x4 ov = o[qt][dt];
      bf16x4 s4 = {f2b(ov.x * rl), f2b(ov.y * rl), f2b(ov.z * rl), f2b(ov.w * rl)};
      *(bf16x4*)(on + ((size_t)b * NS_ + q0 + qt * 16 + q15) * C_ + h * HD_ + dt * 16 + g * 4) = s4;
    }
  }
}

// ---------------------------------------------------------------------------
extern "C" void kernel_launch(void* const* d_in, const int* in_sizes, int n_in,
                              void* d_out, int out_size, void* d_ws, size_t ws_size,
                              hipStream_t stream) {
  const float* x1      = (const float*)d_in[0];
  const float* x2      = (const float*)d_in[1];
  const float* Wq      = (const float*)d_in[2];
  const float* bq      = (const float*)d_in[3];
  const float* Wk      = (const float*)d_in[4];
  const float* bk      = (const float*)d_in[5];
  const float* Wv      = (const float*)d_in[6];
  const float* bv      = (const float*)d_in[7];
  const float* Wo      = (const float*)d_in[8];
  const float* bo      = (const float*)d_in[9];
  const float* off_dw  = (const float*)d_in[10];
  const float* off_dwb = (const float*)d_in[11];
  const float* ln_g    = (const float*)d_in[12];
  const float* ln_b    = (const float*)d_in[13];
  const float* off_w   = (const float*)d_in[14];

  char* base = (char*)d_ws;
  const size_t SZ = (size_t)B_ * C_ * NS_;
  float* q_dC = (float*)base;                   // SZ f32
  short* q_nC = (short*)(base + SZ * 4);        // SZ bf16
  short* samp = (short*)(base + SZ * 6);
  short* k_nC = (short*)(base + SZ * 8);
  short* v_dN = (short*)(base + SZ * 10);
  short* o_nC = (short*)(base + SZ * 12);
  short* x1t  = (short*)(base + SZ * 14);
  short* Wqb  = (short*)(base + SZ * 16);
  short* Wkb  = Wqb + C_ * C_;
  short* Wvb  = Wkb + C_ * C_;
  short* Wob  = Wvb + C_ * C_;

  convw<<<dim3((C_ * C_ + 255) / 256, 4), 256, 0, stream>>>(
      Wq, Wk, Wv, Wo, Wqb, Wkb, Wvb, Wob, C_ * C_);
  transp<<<dim3(NS_ / 32, C_ / 32, B_), 256, 0, stream>>>(x1, x1t);
  gemm_nm<1><<<dim3(8, 3, B_), 256, 0, stream>>>(x1t, Wqb, bq, nullptr, q_nC, q_dC);
  offsample3<<<dim3(B_ * GROUPS_, 64), 256, 0, stream>>>(
      q_dC, x2, off_dw, off_dwb, ln_g, ln_b, off_w, samp);
  gemm_nm<0><<<dim3(8, 3, B_), 256, 0, stream>>>(samp, Wkb, bk, nullptr, k_nC, nullptr);
  gemm_nm<2><<<dim3(8, 3, B_), 256, 0, stream>>>(samp, Wvb, bv, nullptr, v_dN, nullptr);
  attn_mfma<<<dim3(NS_ / 128, B_ * HEADS_), 256, 0, stream>>>(q_nC, k_nC, v_dN, o_nC);
  gemm_nm<3><<<dim3(8, 3, B_), 256, 0, stream>>>(o_nC, Wob, bo, x1, nullptr, (float*)d_out);
}